// Round 1
// baseline (143.279 us; speedup 1.0000x reference)
//
#include <hip/hip_runtime.h>
#include <math.h>

#define NMODES 64
#define SDIM   1024
#define BATCH  256
#define PDIM   4096
#define HDIM   128

// ws layout (floats):
//   basT      : [1024][128]  (s-major, j = 0..63 cos(pi*(j+1)*xs), 64..127 sin(pi*(j-63)*xs))
//   branch_out: [256][128]
#define WS_BAST   0
#define WS_BRANCH (SDIM * HDIM)

// ---------------------------------------------------------------------------
// K1: basis table. 512 blocks x 256 threads = 131072 elements.
// ---------------------------------------------------------------------------
__global__ __launch_bounds__(256) void k_basis(float* __restrict__ basT) {
    int idx = blockIdx.x * 256 + threadIdx.x;
    int s = idx >> 7;
    int j = idx & 127;
    float xs = -1.0f + 2.0f * (float)s / 1023.0f;
    int k = (j & 63) + 1;
    float pk = 3.14159265358979323846f * (float)k;  // rounded to f32, matches jnp.pi*modes
    float ang = pk * xs;
    basT[idx] = (j < 64) ? cosf(ang) : sinf(ang);
}

// ---------------------------------------------------------------------------
// K2: fourier coefficients + branch MLP. 64 blocks x 256 threads, 4 batch
// rows per block. Threads t<128 own output unit j for the MLP phase.
// ---------------------------------------------------------------------------
__global__ __launch_bounds__(256) void k_branch(
    const float* __restrict__ u0, const float* __restrict__ basT,
    const float* __restrict__ bw1, const float* __restrict__ bb1,
    const float* __restrict__ bw2, const float* __restrict__ bb2,
    const float* __restrict__ bw3, const float* __restrict__ bb3,
    float* __restrict__ branch_out) {
    __shared__ float u0s[4][SDIM];        // 16 KB
    __shared__ float part[2][4][HDIM];    // 4 KB
    __shared__ float fL[4][HDIM];         // ping
    __shared__ float hL[4][HDIM];         // pong

    const int t = threadIdx.x;
    const int bb = blockIdx.x * 4;
    const int j = t & 127;
    const int half = t >> 7;

    // stage 4 rows of u0 (coalesced float4)
    for (int q = t; q < SDIM; q += 256) {  // q indexes float4s: 4 rows * 256
        int row = q >> 8, c4 = q & 255;
        ((float4*)u0s[row])[c4] = ((const float4*)(u0 + (size_t)(bb + row) * SDIM))[c4];
    }
    __syncthreads();

    // fourier: thread (j, half) accumulates over its 512 s values
    {
        float a0 = 0.f, a1 = 0.f, a2 = 0.f, a3 = 0.f;
        const int s_lo = half * 512;
        for (int s0 = s_lo; s0 < s_lo + 512; s0 += 4) {
            float w0 = basT[(s0 + 0) * HDIM + j];
            float w1 = basT[(s0 + 1) * HDIM + j];
            float w2 = basT[(s0 + 2) * HDIM + j];
            float w3 = basT[(s0 + 3) * HDIM + j];
            float4 ub0 = *(const float4*)&u0s[0][s0];
            float4 ub1 = *(const float4*)&u0s[1][s0];
            float4 ub2 = *(const float4*)&u0s[2][s0];
            float4 ub3 = *(const float4*)&u0s[3][s0];
            a0 += w0 * ub0.x + w1 * ub0.y + w2 * ub0.z + w3 * ub0.w;
            a1 += w0 * ub1.x + w1 * ub1.y + w2 * ub1.z + w3 * ub1.w;
            a2 += w0 * ub2.x + w1 * ub2.y + w2 * ub2.z + w3 * ub2.w;
            a3 += w0 * ub3.x + w1 * ub3.y + w2 * ub3.z + w3 * ub3.w;
        }
        part[half][0][j] = a0; part[half][1][j] = a1;
        part[half][2][j] = a2; part[half][3][j] = a3;
    }
    __syncthreads();
    if (t < 128) {
        const float sc = 1.0f / (float)SDIM;
        fL[0][j] = (part[0][0][j] + part[1][0][j]) * sc;
        fL[1][j] = (part[0][1][j] + part[1][1][j]) * sc;
        fL[2][j] = (part[0][2][j] + part[1][2][j]) * sc;
        fL[3][j] = (part[0][3][j] + part[1][3][j]) * sc;
    }
    __syncthreads();

    // layer 1: fL -> hL (relu)
    if (t < 128) {
        const float4* wp = (const float4*)(bw1 + (size_t)j * HDIM);
        float bias = bb1[j];
        float c0 = bias, c1 = bias, c2 = bias, c3 = bias;
        for (int i4 = 0; i4 < 32; ++i4) {
            float4 wv = wp[i4];
            float4 x0 = *(const float4*)&fL[0][i4 * 4];
            float4 x1 = *(const float4*)&fL[1][i4 * 4];
            float4 x2 = *(const float4*)&fL[2][i4 * 4];
            float4 x3 = *(const float4*)&fL[3][i4 * 4];
            c0 += wv.x * x0.x + wv.y * x0.y + wv.z * x0.z + wv.w * x0.w;
            c1 += wv.x * x1.x + wv.y * x1.y + wv.z * x1.z + wv.w * x1.w;
            c2 += wv.x * x2.x + wv.y * x2.y + wv.z * x2.z + wv.w * x2.w;
            c3 += wv.x * x3.x + wv.y * x3.y + wv.z * x3.z + wv.w * x3.w;
        }
        hL[0][j] = fmaxf(c0, 0.f); hL[1][j] = fmaxf(c1, 0.f);
        hL[2][j] = fmaxf(c2, 0.f); hL[3][j] = fmaxf(c3, 0.f);
    }
    __syncthreads();

    // layer 2: hL -> fL (relu)
    if (t < 128) {
        const float4* wp = (const float4*)(bw2 + (size_t)j * HDIM);
        float bias = bb2[j];
        float c0 = bias, c1 = bias, c2 = bias, c3 = bias;
        for (int i4 = 0; i4 < 32; ++i4) {
            float4 wv = wp[i4];
            float4 x0 = *(const float4*)&hL[0][i4 * 4];
            float4 x1 = *(const float4*)&hL[1][i4 * 4];
            float4 x2 = *(const float4*)&hL[2][i4 * 4];
            float4 x3 = *(const float4*)&hL[3][i4 * 4];
            c0 += wv.x * x0.x + wv.y * x0.y + wv.z * x0.z + wv.w * x0.w;
            c1 += wv.x * x1.x + wv.y * x1.y + wv.z * x1.z + wv.w * x1.w;
            c2 += wv.x * x2.x + wv.y * x2.y + wv.z * x2.z + wv.w * x2.w;
            c3 += wv.x * x3.x + wv.y * x3.y + wv.z * x3.z + wv.w * x3.w;
        }
        fL[0][j] = fmaxf(c0, 0.f); fL[1][j] = fmaxf(c1, 0.f);
        fL[2][j] = fmaxf(c2, 0.f); fL[3][j] = fmaxf(c3, 0.f);
    }
    __syncthreads();

    // layer 3: fL -> branch_out (no relu)
    if (t < 128) {
        const float4* wp = (const float4*)(bw3 + (size_t)j * HDIM);
        float bias = bb3[j];
        float c0 = bias, c1 = bias, c2 = bias, c3 = bias;
        for (int i4 = 0; i4 < 32; ++i4) {
            float4 wv = wp[i4];
            float4 x0 = *(const float4*)&fL[0][i4 * 4];
            float4 x1 = *(const float4*)&fL[1][i4 * 4];
            float4 x2 = *(const float4*)&fL[2][i4 * 4];
            float4 x3 = *(const float4*)&fL[3][i4 * 4];
            c0 += wv.x * x0.x + wv.y * x0.y + wv.z * x0.z + wv.w * x0.w;
            c1 += wv.x * x1.x + wv.y * x1.y + wv.z * x1.z + wv.w * x1.w;
            c2 += wv.x * x2.x + wv.y * x2.y + wv.z * x2.z + wv.w * x2.w;
            c3 += wv.x * x3.x + wv.y * x3.y + wv.z * x3.z + wv.w * x3.w;
        }
        branch_out[(size_t)(bb + 0) * HDIM + j] = c0;
        branch_out[(size_t)(bb + 1) * HDIM + j] = c1;
        branch_out[(size_t)(bb + 2) * HDIM + j] = c2;
        branch_out[(size_t)(bb + 3) * HDIM + j] = c3;
    }
}

// ---------------------------------------------------------------------------
// K3: trunk MLP for a 16-point tile + final batch x trunk dot. 256 blocks.
// LDS rows padded to 132 floats (33 float4s -> odd quad-group stride,
// conflict-free b128 for lane-varying rows; point-uniform reads broadcast).
// ---------------------------------------------------------------------------
__global__ __launch_bounds__(256) void k_trunk_final(
    const float* __restrict__ xv, const float* __restrict__ tv,
    const float* __restrict__ tw1, const float* __restrict__ tb1,
    const float* __restrict__ tw2, const float* __restrict__ tb2,
    const float* __restrict__ tw3, const float* __restrict__ tb3,
    const float* __restrict__ branch_out, float* __restrict__ out) {
    __shared__ float h1L[16 * 132];
    __shared__ float h2L[16 * 132];
    __shared__ float t3L[16 * 132];
    __shared__ float featL[16][4];
    __shared__ float causL[16];

    const int t = threadIdx.x;
    const int pbase = blockIdx.x * 16;
    const int j = t & 127;
    const int pg = t >> 7;

    if (t < 16) {
        int p = pbase + t;
        float x = xv[p], tt = tv[p];
        float q = tt * tt - x * x;
        float ptime = (q > 0.f) ? sqrtf(q) : 0.f;
        float c = (fabsf(x) <= tt) ? 1.f : 0.f;
        featL[t][0] = x; featL[t][1] = tt; featL[t][2] = ptime; featL[t][3] = c;
        causL[t] = c;
    }
    __syncthreads();

    // layer 1 (4 -> 128)
    {
        float4 w1 = ((const float4*)tw1)[j];
        float b1 = tb1[j];
        for (int p = pg; p < 16; p += 2) {
            float4 f = *(const float4*)featL[p];
            float v = fmaf(w1.x, f.x, fmaf(w1.y, f.y, fmaf(w1.z, f.z, fmaf(w1.w, f.w, b1))));
            h1L[p * 132 + j] = fmaxf(v, 0.f);
        }
    }
    __syncthreads();

    // layer 2 (128 -> 128, relu)
    {
        const float4* wp = (const float4*)(tw2 + (size_t)j * HDIM);
        float bias = tb2[j];
        float acc[8];
#pragma unroll
        for (int q = 0; q < 8; ++q) acc[q] = bias;
        for (int i4 = 0; i4 < 32; ++i4) {
            float4 wv = wp[i4];
#pragma unroll
            for (int q = 0; q < 8; ++q) {
                float4 hv = *(const float4*)&h1L[(pg + q * 2) * 132 + i4 * 4];
                acc[q] += wv.x * hv.x + wv.y * hv.y + wv.z * hv.z + wv.w * hv.w;
            }
        }
#pragma unroll
        for (int q = 0; q < 8; ++q) h2L[(pg + q * 2) * 132 + j] = fmaxf(acc[q], 0.f);
    }
    __syncthreads();

    // layer 3 (128 -> 128, no relu)
    {
        const float4* wp = (const float4*)(tw3 + (size_t)j * HDIM);
        float bias = tb3[j];
        float acc[8];
#pragma unroll
        for (int q = 0; q < 8; ++q) acc[q] = bias;
        for (int i4 = 0; i4 < 32; ++i4) {
            float4 wv = wp[i4];
#pragma unroll
            for (int q = 0; q < 8; ++q) {
                float4 hv = *(const float4*)&h2L[(pg + q * 2) * 132 + i4 * 4];
                acc[q] += wv.x * hv.x + wv.y * hv.y + wv.z * hv.z + wv.w * hv.w;
            }
        }
#pragma unroll
        for (int q = 0; q < 8; ++q) t3L[(pg + q * 2) * 132 + j] = acc[q];
    }
    __syncthreads();

    // final: thread t = batch row; 16 points; coalesced 64B-per-thread stores
    {
        const float4* br = (const float4*)(branch_out + (size_t)t * HDIM);
        float acc[16];
#pragma unroll
        for (int p = 0; p < 16; ++p) acc[p] = 0.f;
        for (int i4 = 0; i4 < 32; ++i4) {
            float4 bv = br[i4];
#pragma unroll
            for (int p = 0; p < 16; ++p) {
                float4 tv4 = *(const float4*)&t3L[p * 132 + i4 * 4];
                acc[p] += bv.x * tv4.x + bv.y * tv4.y + bv.z * tv4.z + bv.w * tv4.w;
            }
        }
        float4* op = (float4*)(out + (size_t)t * PDIM + pbase);
#pragma unroll
        for (int q = 0; q < 4; ++q) {
            op[q] = make_float4(acc[q * 4 + 0] * causL[q * 4 + 0],
                                acc[q * 4 + 1] * causL[q * 4 + 1],
                                acc[q * 4 + 2] * causL[q * 4 + 2],
                                acc[q * 4 + 3] * causL[q * 4 + 3]);
        }
    }
}

// ---------------------------------------------------------------------------
extern "C" void kernel_launch(void* const* d_in, const int* in_sizes, int n_in,
                              void* d_out, int out_size, void* d_ws, size_t ws_size,
                              hipStream_t stream) {
    const float* u0  = (const float*)d_in[0];
    const float* xv  = (const float*)d_in[1];
    const float* tv  = (const float*)d_in[2];
    const float* bw1 = (const float*)d_in[3];
    const float* bb1 = (const float*)d_in[4];
    const float* bw2 = (const float*)d_in[5];
    const float* bb2 = (const float*)d_in[6];
    const float* bw3 = (const float*)d_in[7];
    const float* bb3 = (const float*)d_in[8];
    const float* tw1 = (const float*)d_in[9];
    const float* tb1 = (const float*)d_in[10];
    const float* tw2 = (const float*)d_in[11];
    const float* tb2 = (const float*)d_in[12];
    const float* tw3 = (const float*)d_in[13];
    const float* tb3 = (const float*)d_in[14];

    float* ws = (float*)d_ws;
    float* basT = ws + WS_BAST;
    float* branch_out = ws + WS_BRANCH;
    float* out = (float*)d_out;

    hipLaunchKernelGGL(k_basis, dim3((SDIM * HDIM) / 256), dim3(256), 0, stream, basT);
    hipLaunchKernelGGL(k_branch, dim3(BATCH / 4), dim3(256), 0, stream,
                       u0, basT, bw1, bb1, bw2, bb2, bw3, bb3, branch_out);
    hipLaunchKernelGGL(k_trunk_final, dim3(PDIM / 16), dim3(256), 0, stream,
                       xv, tv, tw1, tb1, tw2, tb2, tw3, tb3, branch_out, out);
}

// Round 2
// 129.234 us; speedup vs baseline: 1.1087x; 1.1087x over previous
//
#include <hip/hip_runtime.h>
#include <math.h>

#define NMODES 64
#define SDIM   1024
#define BATCH  256
#define PDIM   4096
#define HDIM   128

// ws layout (floats):
//   basT   @ 0       : [1024][128]  (s-major; j<64 -> cos(pi*(j+1)*xs), j>=64 -> sin)
//   branch @ 131072  : [256][128]
//   t3     @ 163840  : [4096][128]  trunk layer-3 output (pre-causal)
#define WS_BAST   0
#define WS_BRANCH (SDIM * HDIM)
#define WS_T3     (WS_BRANCH + BATCH * HDIM)

// ---------------------------------------------------------------------------
// K1: fused basis table (blocks 0..511) + trunk MLP (blocks 512..767).
// Independent work items packed into one launch for full-chip utilization.
// ---------------------------------------------------------------------------
__global__ __launch_bounds__(256) void k_basis_trunk(
    const float* __restrict__ xv, const float* __restrict__ tv,
    const float* __restrict__ tw1, const float* __restrict__ tb1,
    const float* __restrict__ tw2, const float* __restrict__ tb2,
    const float* __restrict__ tw3, const float* __restrict__ tb3,
    float* __restrict__ basT, float* __restrict__ t3g) {
    __shared__ float h1L[16 * 132];
    __shared__ float h2L[16 * 132];
    __shared__ float featL[16][4];

    const int t = threadIdx.x;

    if (blockIdx.x < 512) {
        // ---- basis table ----
        int idx = blockIdx.x * 256 + t;
        int s = idx >> 7;
        int j = idx & 127;
        float xs = -1.0f + 2.0f * (float)s / 1023.0f;
        int k = (j & 63) + 1;
        float pk = 3.14159265358979323846f * (float)k;
        float ang = pk * xs;
        basT[idx] = (j < 64) ? cosf(ang) : sinf(ang);
        return;
    }

    // ---- trunk MLP, 16 points per block ----
    const int pbase = (blockIdx.x - 512) * 16;
    const int j = t & 127;
    const int pg = t >> 7;

    if (t < 16) {
        int p = pbase + t;
        float x = xv[p], tt = tv[p];
        float q = tt * tt - x * x;
        float ptime = (q > 0.f) ? sqrtf(q) : 0.f;
        float c = (fabsf(x) <= tt) ? 1.f : 0.f;
        featL[t][0] = x; featL[t][1] = tt; featL[t][2] = ptime; featL[t][3] = c;
    }
    __syncthreads();

    // layer 1 (4 -> 128)
    {
        float4 w1 = ((const float4*)tw1)[j];
        float b1 = tb1[j];
        for (int p = pg; p < 16; p += 2) {
            float4 f = *(const float4*)featL[p];
            float v = fmaf(w1.x, f.x, fmaf(w1.y, f.y, fmaf(w1.z, f.z, fmaf(w1.w, f.w, b1))));
            h1L[p * 132 + j] = fmaxf(v, 0.f);
        }
    }
    __syncthreads();

    // layer 2 (128 -> 128, relu). LDS reads are wave-uniform -> broadcast.
    {
        const float4* wp = (const float4*)(tw2 + (size_t)j * HDIM);
        float bias = tb2[j];
        float acc[8];
#pragma unroll
        for (int q = 0; q < 8; ++q) acc[q] = bias;
        for (int i4 = 0; i4 < 32; ++i4) {
            float4 wv = wp[i4];
#pragma unroll
            for (int q = 0; q < 8; ++q) {
                float4 hv = *(const float4*)&h1L[(pg + q * 2) * 132 + i4 * 4];
                acc[q] += wv.x * hv.x + wv.y * hv.y + wv.z * hv.z + wv.w * hv.w;
            }
        }
#pragma unroll
        for (int q = 0; q < 8; ++q) h2L[(pg + q * 2) * 132 + j] = fmaxf(acc[q], 0.f);
    }
    __syncthreads();

    // layer 3 (128 -> 128, no relu) -> global t3 (coalesced 512B stores)
    {
        const float4* wp = (const float4*)(tw3 + (size_t)j * HDIM);
        float bias = tb3[j];
        float acc[8];
#pragma unroll
        for (int q = 0; q < 8; ++q) acc[q] = bias;
        for (int i4 = 0; i4 < 32; ++i4) {
            float4 wv = wp[i4];
#pragma unroll
            for (int q = 0; q < 8; ++q) {
                float4 hv = *(const float4*)&h2L[(pg + q * 2) * 132 + i4 * 4];
                acc[q] += wv.x * hv.x + wv.y * hv.y + wv.z * hv.z + wv.w * hv.w;
            }
        }
#pragma unroll
        for (int q = 0; q < 8; ++q)
            t3g[(size_t)(pbase + pg + q * 2) * HDIM + j] = acc[q];
    }
}

// ---------------------------------------------------------------------------
// K2: fourier + branch MLP. 128 blocks x 2 batch rows. u0 LDS reads are
// wave-uniform broadcasts; basT reads coalesced (256B per wave per load).
// ---------------------------------------------------------------------------
__global__ __launch_bounds__(256) void k_branch(
    const float* __restrict__ u0, const float* __restrict__ basT,
    const float* __restrict__ bw1, const float* __restrict__ bb1,
    const float* __restrict__ bw2, const float* __restrict__ bb2,
    const float* __restrict__ bw3, const float* __restrict__ bb3,
    float* __restrict__ branch_out) {
    __shared__ float u0s[2][SDIM];      // 8 KB
    __shared__ float part[2][2][HDIM];  // 2 KB
    __shared__ float fr[2][HDIM];
    __shared__ float hh[2][HDIM];

    const int t = threadIdx.x;
    const int bb = blockIdx.x * 2;
    const int j = t & 127;
    const int half = t >> 7;

    // stage 2 rows of u0 (coalesced float4)
    {
        int flat0 = t;          // float4 index within 512
        int row0 = flat0 >> 8, c40 = flat0 & 255;
        ((float4*)u0s[row0])[c40] = ((const float4*)(u0 + (size_t)(bb + row0) * SDIM))[c40];
        int flat1 = t + 256;
        int row1 = flat1 >> 8, c41 = flat1 & 255;
        ((float4*)u0s[row1])[c41] = ((const float4*)(u0 + (size_t)(bb + row1) * SDIM))[c41];
    }
    __syncthreads();

    // fourier: thread (j, half) accumulates its 512 s values
    {
        float a0 = 0.f, a1 = 0.f;
        const float* bp = basT + j;
        const int s_lo = half * 512;
        for (int s0 = s_lo; s0 < s_lo + 512; s0 += 4) {
            float w0 = bp[(s0 + 0) * HDIM];
            float w1 = bp[(s0 + 1) * HDIM];
            float w2 = bp[(s0 + 2) * HDIM];
            float w3 = bp[(s0 + 3) * HDIM];
            float4 ua = *(const float4*)&u0s[0][s0];   // uniform -> broadcast
            float4 ub = *(const float4*)&u0s[1][s0];
            a0 += w0 * ua.x + w1 * ua.y + w2 * ua.z + w3 * ua.w;
            a1 += w0 * ub.x + w1 * ub.y + w2 * ub.z + w3 * ub.w;
        }
        part[half][0][j] = a0;
        part[half][1][j] = a1;
    }
    __syncthreads();
    if (t < 128) {
        const float sc = 1.0f / (float)SDIM;
        fr[0][j] = (part[0][0][j] + part[1][0][j]) * sc;
        fr[1][j] = (part[0][1][j] + part[1][1][j]) * sc;
    }
    __syncthreads();

    // 3 MLP layers, thread j owns output unit j (t<128 active; tiny phase)
    if (t < 128) {
        // layer 1
        {
            const float4* wp = (const float4*)(bw1 + (size_t)j * HDIM);
            float c0 = bb1[j], c1 = c0;
            for (int i4 = 0; i4 < 32; ++i4) {
                float4 wv = wp[i4];
                float4 x0 = *(const float4*)&fr[0][i4 * 4];
                float4 x1 = *(const float4*)&fr[1][i4 * 4];
                c0 += wv.x * x0.x + wv.y * x0.y + wv.z * x0.z + wv.w * x0.w;
                c1 += wv.x * x1.x + wv.y * x1.y + wv.z * x1.z + wv.w * x1.w;
            }
            hh[0][j] = fmaxf(c0, 0.f); hh[1][j] = fmaxf(c1, 0.f);
        }
        __syncthreads();
        // layer 2
        {
            const float4* wp = (const float4*)(bw2 + (size_t)j * HDIM);
            float c0 = bb2[j], c1 = c0;
            for (int i4 = 0; i4 < 32; ++i4) {
                float4 wv = wp[i4];
                float4 x0 = *(const float4*)&hh[0][i4 * 4];
                float4 x1 = *(const float4*)&hh[1][i4 * 4];
                c0 += wv.x * x0.x + wv.y * x0.y + wv.z * x0.z + wv.w * x0.w;
                c1 += wv.x * x1.x + wv.y * x1.y + wv.z * x1.z + wv.w * x1.w;
            }
            fr[0][j] = fmaxf(c0, 0.f); fr[1][j] = fmaxf(c1, 0.f);
        }
        __syncthreads();
        // layer 3 -> branch ws
        {
            const float4* wp = (const float4*)(bw3 + (size_t)j * HDIM);
            float c0 = bb3[j], c1 = c0;
            for (int i4 = 0; i4 < 32; ++i4) {
                float4 wv = wp[i4];
                float4 x0 = *(const float4*)&fr[0][i4 * 4];
                float4 x1 = *(const float4*)&fr[1][i4 * 4];
                c0 += wv.x * x0.x + wv.y * x0.y + wv.z * x0.z + wv.w * x0.w;
                c1 += wv.x * x1.x + wv.y * x1.y + wv.z * x1.z + wv.w * x1.w;
            }
            branch_out[(size_t)(bb + 0) * HDIM + j] = c0;
            branch_out[(size_t)(bb + 1) * HDIM + j] = c1;
        }
    } else {
        __syncthreads();
        __syncthreads();
    }
}

// ---------------------------------------------------------------------------
// K3: final GEMM out(256x4096) = branch(256x128) @ t3^T, * causal.
// 256 blocks = 4 row-tiles x 64 col-tiles of 64x64. 4x4 register tile.
// LDS rows padded to 68 floats -> <=2-way bank conflicts (free per m136).
// ---------------------------------------------------------------------------
#define LDP 68
__global__ __launch_bounds__(256) void k_final(
    const float* __restrict__ br_g, const float* __restrict__ t3g,
    const float* __restrict__ xv, const float* __restrict__ tv,
    float* __restrict__ out) {
    __shared__ float brL[64 * LDP];   // 17.4 KB
    __shared__ float ttL[64 * LDP];   // 17.4 KB
    __shared__ float causL[64];

    const int t = threadIdx.x;
    const int rb = blockIdx.x >> 6;          // 0..3 (batch tile)
    const int cb = blockIdx.x & 63;          // 0..63 (point tile)
    const int tx = t & 15;                   // point sub-index
    const int ty = t >> 4;                   // batch sub-index

    if (t < 64) {
        int p = cb * 64 + t;
        float x = xv[p], tt = tv[p];
        causL[t] = (fabsf(x) <= tt) ? 1.f : 0.f;
    }

    float acc[4][4];
#pragma unroll
    for (int r = 0; r < 4; ++r)
#pragma unroll
        for (int c = 0; c < 4; ++c) acc[r][c] = 0.f;

    for (int kc = 0; kc < HDIM; kc += 64) {
        // stage 64x64 chunks of branch and t3 (4 float4 each per thread)
        __syncthreads();
#pragma unroll
        for (int it = 0; it < 4; ++it) {
            int flat = t + 256 * it;         // 0..1023 float4 slots
            int row = flat >> 4, c4 = flat & 15;
            *(float4*)&brL[row * LDP + c4 * 4] =
                *(const float4*)&br_g[(size_t)(rb * 64 + row) * HDIM + kc + c4 * 4];
            *(float4*)&ttL[row * LDP + c4 * 4] =
                *(const float4*)&t3g[(size_t)(cb * 64 + row) * HDIM + kc + c4 * 4];
        }
        __syncthreads();

#pragma unroll
        for (int k4 = 0; k4 < 16; ++k4) {
            float4 a[4], b[4];
#pragma unroll
            for (int r = 0; r < 4; ++r)
                a[r] = *(const float4*)&brL[(ty + 16 * r) * LDP + k4 * 4];
#pragma unroll
            for (int c = 0; c < 4; ++c)
                b[c] = *(const float4*)&ttL[(tx + 16 * c) * LDP + k4 * 4];
#pragma unroll
            for (int r = 0; r < 4; ++r)
#pragma unroll
                for (int c = 0; c < 4; ++c) {
                    acc[r][c] += a[r].x * b[c].x + a[r].y * b[c].y +
                                 a[r].z * b[c].z + a[r].w * b[c].w;
                }
        }
    }

    // epilogue: apply causal, store
#pragma unroll
    for (int r = 0; r < 4; ++r) {
        int row = rb * 64 + ty + 16 * r;
#pragma unroll
        for (int c = 0; c < 4; ++c) {
            int col = tx + 16 * c;
            out[(size_t)row * PDIM + cb * 64 + col] = acc[r][c] * causL[col];
        }
    }
}

// ---------------------------------------------------------------------------
extern "C" void kernel_launch(void* const* d_in, const int* in_sizes, int n_in,
                              void* d_out, int out_size, void* d_ws, size_t ws_size,
                              hipStream_t stream) {
    const float* u0  = (const float*)d_in[0];
    const float* xv  = (const float*)d_in[1];
    const float* tv  = (const float*)d_in[2];
    const float* bw1 = (const float*)d_in[3];
    const float* bb1 = (const float*)d_in[4];
    const float* bw2 = (const float*)d_in[5];
    const float* bb2 = (const float*)d_in[6];
    const float* bw3 = (const float*)d_in[7];
    const float* bb3 = (const float*)d_in[8];
    const float* tw1 = (const float*)d_in[9];
    const float* tb1 = (const float*)d_in[10];
    const float* tw2 = (const float*)d_in[11];
    const float* tb2 = (const float*)d_in[12];
    const float* tw3 = (const float*)d_in[13];
    const float* tb3 = (const float*)d_in[14];

    float* ws = (float*)d_ws;
    float* basT = ws + WS_BAST;
    float* branch_out = ws + WS_BRANCH;
    float* t3g = ws + WS_T3;
    float* out = (float*)d_out;

    hipLaunchKernelGGL(k_basis_trunk, dim3(768), dim3(256), 0, stream,
                       xv, tv, tw1, tb1, tw2, tb2, tw3, tb3, basT, t3g);
    hipLaunchKernelGGL(k_branch, dim3(BATCH / 2), dim3(256), 0, stream,
                       u0, basT, bw1, bb1, bw2, bb2, bw3, bb3, branch_out);
    hipLaunchKernelGGL(k_final, dim3(256), dim3(256), 0, stream,
                       branch_out, t3g, xv, tv, out);
}

// Round 3
// 120.427 us; speedup vs baseline: 1.1898x; 1.0731x over previous
//
#include <hip/hip_runtime.h>
#include <hip/hip_fp16.h>
#include <math.h>

#define NMODES 64
#define SDIM   1024
#define BATCH  256
#define PDIM   4096
#define HDIM   128

typedef _Float16 half8 __attribute__((ext_vector_type(8)));
typedef float f32x4 __attribute__((ext_vector_type(4)));

// ws layout (bytes):
//   basT  @ 0       : f32 [1024][128]   (512 KB)
//   branch@ 524288  : f16 [256][128]    (64 KB)
//   t3    @ 589824  : f16 [4096][128]   (1 MB)
#define WSB_BAST   0
#define WSB_BRANCH (SDIM * HDIM * 4)
#define WSB_T3     (WSB_BRANCH + BATCH * HDIM * 2)

// ---------------------------------------------------------------------------
// K1: fused basis table (blocks 0..511) + trunk MLP (blocks 512..767).
// Trunk layer-3 output stored as f16 (consumed by MFMA k_final).
// ---------------------------------------------------------------------------
__global__ __launch_bounds__(256) void k_basis_trunk(
    const float* __restrict__ xv, const float* __restrict__ tv,
    const float* __restrict__ tw1, const float* __restrict__ tb1,
    const float* __restrict__ tw2, const float* __restrict__ tb2,
    const float* __restrict__ tw3, const float* __restrict__ tb3,
    float* __restrict__ basT, __half* __restrict__ t3g) {
    __shared__ float h1L[16 * 132];
    __shared__ float h2L[16 * 132];
    __shared__ float featL[16][4];

    const int t = threadIdx.x;

    if (blockIdx.x < 512) {
        int idx = blockIdx.x * 256 + t;
        int s = idx >> 7;
        int j = idx & 127;
        float xs = -1.0f + 2.0f * (float)s / 1023.0f;
        int k = (j & 63) + 1;
        float pk = 3.14159265358979323846f * (float)k;
        float ang = pk * xs;
        basT[idx] = (j < 64) ? cosf(ang) : sinf(ang);
        return;
    }

    const int pbase = (blockIdx.x - 512) * 16;
    const int j = t & 127;
    const int pg = t >> 7;

    if (t < 16) {
        int p = pbase + t;
        float x = xv[p], tt = tv[p];
        float q = tt * tt - x * x;
        float ptime = (q > 0.f) ? sqrtf(q) : 0.f;
        float c = (fabsf(x) <= tt) ? 1.f : 0.f;
        featL[t][0] = x; featL[t][1] = tt; featL[t][2] = ptime; featL[t][3] = c;
    }
    __syncthreads();

    // layer 1 (4 -> 128)
    {
        float4 w1 = ((const float4*)tw1)[j];
        float b1 = tb1[j];
        for (int p = pg; p < 16; p += 2) {
            float4 f = *(const float4*)featL[p];
            float v = fmaf(w1.x, f.x, fmaf(w1.y, f.y, fmaf(w1.z, f.z, fmaf(w1.w, f.w, b1))));
            h1L[p * 132 + j] = fmaxf(v, 0.f);
        }
    }
    __syncthreads();

    // layer 2 (128 -> 128, relu)
    {
        const float4* wp = (const float4*)(tw2 + (size_t)j * HDIM);
        float bias = tb2[j];
        float acc[8];
#pragma unroll
        for (int q = 0; q < 8; ++q) acc[q] = bias;
        for (int i4 = 0; i4 < 32; ++i4) {
            float4 wv = wp[i4];
#pragma unroll
            for (int q = 0; q < 8; ++q) {
                float4 hv = *(const float4*)&h1L[(pg + q * 2) * 132 + i4 * 4];
                acc[q] += wv.x * hv.x + wv.y * hv.y + wv.z * hv.z + wv.w * hv.w;
            }
        }
#pragma unroll
        for (int q = 0; q < 8; ++q) h2L[(pg + q * 2) * 132 + j] = fmaxf(acc[q], 0.f);
    }
    __syncthreads();

    // layer 3 (128 -> 128) -> f16 t3
    {
        const float4* wp = (const float4*)(tw3 + (size_t)j * HDIM);
        float bias = tb3[j];
        float acc[8];
#pragma unroll
        for (int q = 0; q < 8; ++q) acc[q] = bias;
        for (int i4 = 0; i4 < 32; ++i4) {
            float4 wv = wp[i4];
#pragma unroll
            for (int q = 0; q < 8; ++q) {
                float4 hv = *(const float4*)&h2L[(pg + q * 2) * 132 + i4 * 4];
                acc[q] += wv.x * hv.x + wv.y * hv.y + wv.z * hv.z + wv.w * hv.w;
            }
        }
#pragma unroll
        for (int q = 0; q < 8; ++q)
            t3g[(size_t)(pbase + pg + q * 2) * HDIM + j] = __float2half(acc[q]);
    }
}

// ---------------------------------------------------------------------------
// K2: fourier + branch MLP. 128 blocks x 2 batch rows. Branch out as f16.
// ---------------------------------------------------------------------------
__global__ __launch_bounds__(256) void k_branch(
    const float* __restrict__ u0, const float* __restrict__ basT,
    const float* __restrict__ bw1, const float* __restrict__ bb1,
    const float* __restrict__ bw2, const float* __restrict__ bb2,
    const float* __restrict__ bw3, const float* __restrict__ bb3,
    __half* __restrict__ branch_out) {
    __shared__ float u0s[2][SDIM];
    __shared__ float part[2][2][HDIM];
    __shared__ float fr[2][HDIM];
    __shared__ float hh[2][HDIM];

    const int t = threadIdx.x;
    const int bb = blockIdx.x * 2;
    const int j = t & 127;
    const int half = t >> 7;

    {
        int flat0 = t;
        int row0 = flat0 >> 8, c40 = flat0 & 255;
        ((float4*)u0s[row0])[c40] = ((const float4*)(u0 + (size_t)(bb + row0) * SDIM))[c40];
        int flat1 = t + 256;
        int row1 = flat1 >> 8, c41 = flat1 & 255;
        ((float4*)u0s[row1])[c41] = ((const float4*)(u0 + (size_t)(bb + row1) * SDIM))[c41];
    }
    __syncthreads();

    {
        float a0 = 0.f, a1 = 0.f;
        const float* bp = basT + j;
        const int s_lo = half * 512;
        for (int s0 = s_lo; s0 < s_lo + 512; s0 += 4) {
            float w0 = bp[(s0 + 0) * HDIM];
            float w1 = bp[(s0 + 1) * HDIM];
            float w2 = bp[(s0 + 2) * HDIM];
            float w3 = bp[(s0 + 3) * HDIM];
            float4 ua = *(const float4*)&u0s[0][s0];
            float4 ub = *(const float4*)&u0s[1][s0];
            a0 += w0 * ua.x + w1 * ua.y + w2 * ua.z + w3 * ua.w;
            a1 += w0 * ub.x + w1 * ub.y + w2 * ub.z + w3 * ub.w;
        }
        part[half][0][j] = a0;
        part[half][1][j] = a1;
    }
    __syncthreads();
    if (t < 128) {
        const float sc = 1.0f / (float)SDIM;
        fr[0][j] = (part[0][0][j] + part[1][0][j]) * sc;
        fr[1][j] = (part[0][1][j] + part[1][1][j]) * sc;
    }
    __syncthreads();

    if (t < 128) {
        {
            const float4* wp = (const float4*)(bw1 + (size_t)j * HDIM);
            float c0 = bb1[j], c1 = c0;
            for (int i4 = 0; i4 < 32; ++i4) {
                float4 wv = wp[i4];
                float4 x0 = *(const float4*)&fr[0][i4 * 4];
                float4 x1 = *(const float4*)&fr[1][i4 * 4];
                c0 += wv.x * x0.x + wv.y * x0.y + wv.z * x0.z + wv.w * x0.w;
                c1 += wv.x * x1.x + wv.y * x1.y + wv.z * x1.z + wv.w * x1.w;
            }
            hh[0][j] = fmaxf(c0, 0.f); hh[1][j] = fmaxf(c1, 0.f);
        }
        __syncthreads();
        {
            const float4* wp = (const float4*)(bw2 + (size_t)j * HDIM);
            float c0 = bb2[j], c1 = c0;
            for (int i4 = 0; i4 < 32; ++i4) {
                float4 wv = wp[i4];
                float4 x0 = *(const float4*)&hh[0][i4 * 4];
                float4 x1 = *(const float4*)&hh[1][i4 * 4];
                c0 += wv.x * x0.x + wv.y * x0.y + wv.z * x0.z + wv.w * x0.w;
                c1 += wv.x * x1.x + wv.y * x1.y + wv.z * x1.z + wv.w * x1.w;
            }
            fr[0][j] = fmaxf(c0, 0.f); fr[1][j] = fmaxf(c1, 0.f);
        }
        __syncthreads();
        {
            const float4* wp = (const float4*)(bw3 + (size_t)j * HDIM);
            float c0 = bb3[j], c1 = c0;
            for (int i4 = 0; i4 < 32; ++i4) {
                float4 wv = wp[i4];
                float4 x0 = *(const float4*)&fr[0][i4 * 4];
                float4 x1 = *(const float4*)&fr[1][i4 * 4];
                c0 += wv.x * x0.x + wv.y * x0.y + wv.z * x0.z + wv.w * x0.w;
                c1 += wv.x * x1.x + wv.y * x1.y + wv.z * x1.z + wv.w * x1.w;
            }
            branch_out[(size_t)(bb + 0) * HDIM + j] = __float2half(c0);
            branch_out[(size_t)(bb + 1) * HDIM + j] = __float2half(c1);
        }
    } else {
        __syncthreads();
        __syncthreads();
    }
}

// ---------------------------------------------------------------------------
// K3: final einsum via fp16 MFMA. out(256x4096) = br(256x128) @ t3^T * causal.
// 256 blocks (4 batch-tiles x 64 point-tiles of 64x64). Wave w owns rows
// 16w..16w+15 x all 64 cols; 16 mfma_f32_16x16x32_f16 per wave.
// LDS row pad: 144 halves (288 B) -> b128 frag reads at the 8-phase floor.
// ---------------------------------------------------------------------------
#define LDH 144
__global__ __launch_bounds__(256) void k_final(
    const __half* __restrict__ br_g, const __half* __restrict__ t3g,
    const float* __restrict__ xv, const float* __restrict__ tv,
    float* __restrict__ out) {
    __shared__ _Float16 brL[64 * LDH];   // 18.4 KB
    __shared__ _Float16 ttL[64 * LDH];   // 18.4 KB
    __shared__ float causL[64];

    const int t = threadIdx.x;
    const int rb = blockIdx.x >> 6;   // batch tile 0..3
    const int cb = blockIdx.x & 63;   // point tile 0..63

    if (t < 64) {
        int p = cb * 64 + t;
        float x = xv[p], tt = tv[p];
        causL[t] = (fabsf(x) <= tt) ? 1.f : 0.f;
    }

    // stage both 64x128 f16 tiles (16B chunks, coalesced)
#pragma unroll
    for (int it = 0; it < 4; ++it) {
        int flat = t + 256 * it;      // 0..1023
        int row = flat >> 4, c = flat & 15;
        *(float4*)&brL[row * LDH + c * 8] =
            *(const float4*)&br_g[(size_t)(rb * 64 + row) * HDIM + c * 8];
        *(float4*)&ttL[row * LDH + c * 8] =
            *(const float4*)&t3g[(size_t)(cb * 64 + row) * HDIM + c * 8];
    }
    __syncthreads();

    const int lane = t & 63;
    const int w = t >> 6;             // wave 0..3
    const int lm = lane & 15;         // frag row
    const int q = lane >> 4;          // quad -> k-subchunk

    f32x4 acc[4] = {f32x4{0,0,0,0}, f32x4{0,0,0,0}, f32x4{0,0,0,0}, f32x4{0,0,0,0}};

    const _Float16* aBase = &brL[(16 * w + lm) * LDH + q * 8];
#pragma unroll
    for (int ks = 0; ks < 4; ++ks) {
        half8 af = *(const half8*)(aBase + ks * 32);
#pragma unroll
        for (int jt = 0; jt < 4; ++jt) {
            half8 bf = *(const half8*)&ttL[(16 * jt + lm) * LDH + q * 8 + ks * 32];
            acc[jt] = __builtin_amdgcn_mfma_f32_16x16x32_f16(af, bf, acc[jt], 0, 0, 0);
        }
    }

    // epilogue: C/D layout col=lane&15, row=(lane>>4)*4+reg (m89-verified)
#pragma unroll
    for (int jt = 0; jt < 4; ++jt) {
        int col = cb * 64 + 16 * jt + lm;
        float cz = causL[16 * jt + lm];
#pragma unroll
        for (int e = 0; e < 4; ++e) {
            int row = rb * 64 + 16 * w + q * 4 + e;
            out[(size_t)row * PDIM + col] = acc[jt][e] * cz;
        }
    }
}

// ---------------------------------------------------------------------------
extern "C" void kernel_launch(void* const* d_in, const int* in_sizes, int n_in,
                              void* d_out, int out_size, void* d_ws, size_t ws_size,
                              hipStream_t stream) {
    const float* u0  = (const float*)d_in[0];
    const float* xv  = (const float*)d_in[1];
    const float* tv  = (const float*)d_in[2];
    const float* bw1 = (const float*)d_in[3];
    const float* bb1 = (const float*)d_in[4];
    const float* bw2 = (const float*)d_in[5];
    const float* bb2 = (const float*)d_in[6];
    const float* bw3 = (const float*)d_in[7];
    const float* bb3 = (const float*)d_in[8];
    const float* tw1 = (const float*)d_in[9];
    const float* tb1 = (const float*)d_in[10];
    const float* tw2 = (const float*)d_in[11];
    const float* tb2 = (const float*)d_in[12];
    const float* tw3 = (const float*)d_in[13];
    const float* tb3 = (const float*)d_in[14];

    char* wsb = (char*)d_ws;
    float*  basT       = (float*)(wsb + WSB_BAST);
    __half* branch_out = (__half*)(wsb + WSB_BRANCH);
    __half* t3g        = (__half*)(wsb + WSB_T3);
    float* out = (float*)d_out;

    hipLaunchKernelGGL(k_basis_trunk, dim3(768), dim3(256), 0, stream,
                       xv, tv, tw1, tb1, tw2, tb2, tw3, tb3, basT, t3g);
    hipLaunchKernelGGL(k_branch, dim3(BATCH / 2), dim3(256), 0, stream,
                       u0, basT, bw1, bb1, bw2, bb2, bw3, bb3, branch_out);
    hipLaunchKernelGGL(k_final, dim3(256), dim3(256), 0, stream,
                       branch_out, t3g, xv, tv, out);
}

// Round 4
// 107.331 us; speedup vs baseline: 1.3349x; 1.1220x over previous
//
#include <hip/hip_runtime.h>
#include <hip/hip_fp16.h>
#include <math.h>

#define NMODES 64
#define SDIM   1024
#define BATCH  256
#define PDIM   4096
#define HDIM   128

typedef _Float16 half8 __attribute__((ext_vector_type(8)));
typedef float f32x4 __attribute__((ext_vector_type(4)));

// ws layout (bytes): no more basis table — fourier basis is generated in-loop
// via v_cos/v_sin (revolutions semantics).
//   branch @ 0     : f16 [256][128]    (64 KB)
//   t3     @ 65536 : f16 [4096][128]   (1 MB)
#define WSB_BRANCH 0
#define WSB_T3     (BATCH * HDIM * 2)

// ---------------------------------------------------------------------------
// K1 (fused, 384 blocks):
//   blocks 0..255   : trunk MLP, 16 points each -> t3 (f16)
//   blocks 256..383 : fourier (hw-cos recurrence) + branch MLP, 2 rows each
// Independent work; one dispatch instead of basis+trunk / branch.
// ---------------------------------------------------------------------------
__global__ __launch_bounds__(256) void k_fused(
    const float* __restrict__ u0,
    const float* __restrict__ xv, const float* __restrict__ tv,
    const float* __restrict__ bw1, const float* __restrict__ bb1,
    const float* __restrict__ bw2, const float* __restrict__ bb2,
    const float* __restrict__ bw3, const float* __restrict__ bb3,
    const float* __restrict__ tw1, const float* __restrict__ tb1,
    const float* __restrict__ tw2, const float* __restrict__ tb2,
    const float* __restrict__ tw3, const float* __restrict__ tb3,
    __half* __restrict__ branch_out, __half* __restrict__ t3g) {
    __shared__ float h1L[16 * 132];
    __shared__ float h2L[16 * 132];
    __shared__ float featL[16][4];
    __shared__ float u0s[2][SDIM];
    __shared__ float part[2][2][HDIM];
    __shared__ float fr[2][HDIM];
    __shared__ float hh[2][HDIM];

    const int t = threadIdx.x;

    if (blockIdx.x < 256) {
        // ================= trunk MLP (16 points) =================
        const int pbase = blockIdx.x * 16;
        const int j = t & 127;
        const int pg = t >> 7;

        if (t < 16) {
            int p = pbase + t;
            float x = xv[p], tt = tv[p];
            float q = tt * tt - x * x;
            float ptime = (q > 0.f) ? sqrtf(q) : 0.f;
            float c = (fabsf(x) <= tt) ? 1.f : 0.f;
            featL[t][0] = x; featL[t][1] = tt; featL[t][2] = ptime; featL[t][3] = c;
        }
        __syncthreads();

        // layer 1 (4 -> 128)
        {
            float4 w1 = ((const float4*)tw1)[j];
            float b1 = tb1[j];
            for (int p = pg; p < 16; p += 2) {
                float4 f = *(const float4*)featL[p];
                float v = fmaf(w1.x, f.x, fmaf(w1.y, f.y, fmaf(w1.z, f.z, fmaf(w1.w, f.w, b1))));
                h1L[p * 132 + j] = fmaxf(v, 0.f);
            }
        }
        __syncthreads();

        // layer 2 (128 -> 128, relu)
        {
            const float4* wp = (const float4*)(tw2 + (size_t)j * HDIM);
            float bias = tb2[j];
            float acc[8];
#pragma unroll
            for (int q = 0; q < 8; ++q) acc[q] = bias;
            for (int i4 = 0; i4 < 32; ++i4) {
                float4 wv = wp[i4];
#pragma unroll
                for (int q = 0; q < 8; ++q) {
                    float4 hv = *(const float4*)&h1L[(pg + q * 2) * 132 + i4 * 4];
                    acc[q] += wv.x * hv.x + wv.y * hv.y + wv.z * hv.z + wv.w * hv.w;
                }
            }
#pragma unroll
            for (int q = 0; q < 8; ++q) h2L[(pg + q * 2) * 132 + j] = fmaxf(acc[q], 0.f);
        }
        __syncthreads();

        // layer 3 (128 -> 128) -> f16 t3
        {
            const float4* wp = (const float4*)(tw3 + (size_t)j * HDIM);
            float bias = tb3[j];
            float acc[8];
#pragma unroll
            for (int q = 0; q < 8; ++q) acc[q] = bias;
            for (int i4 = 0; i4 < 32; ++i4) {
                float4 wv = wp[i4];
#pragma unroll
                for (int q = 0; q < 8; ++q) {
                    float4 hv = *(const float4*)&h2L[(pg + q * 2) * 132 + i4 * 4];
                    acc[q] += wv.x * hv.x + wv.y * hv.y + wv.z * hv.z + wv.w * hv.w;
                }
            }
#pragma unroll
            for (int q = 0; q < 8; ++q)
                t3g[(size_t)(pbase + pg + q * 2) * HDIM + j] = __float2half(acc[q]);
        }
        return;
    }

    // ================= fourier + branch MLP (2 rows) =================
    const int bb = (blockIdx.x - 256) * 2;
    const int j = t & 127;
    const int half = t >> 7;

    // stage 2 rows of u0 (coalesced float4)
    {
        int flat0 = t;
        int row0 = flat0 >> 8, c40 = flat0 & 255;
        ((float4*)u0s[row0])[c40] = ((const float4*)(u0 + (size_t)(bb + row0) * SDIM))[c40];
        int flat1 = t + 256;
        int row1 = flat1 >> 8, c41 = flat1 & 255;
        ((float4*)u0s[row1])[c41] = ((const float4*)(u0 + (size_t)(bb + row1) * SDIM))[c41];
    }
    __syncthreads();

    // fourier: basis generated in-register. angle in REVOLUTIONS:
    //   basis_s = cos(2*pi * (k*xs_s/2))  (sin for j>=64)
    //   xs_s = -1 + 2s/1023;  a_{s+1} = fract-stabilized a_s + k/1023
    // v_cos_f32/v_sin_f32 take revolutions; fract keeps |a| small so the
    // 512-step recurrence drift stays ~1e-5 rad (output impact <1e-6).
    {
        const int kmode = (j & 63) + 1;
        const int s_lo = half * 512;
        float xs0 = -1.0f + 2.0f * (float)s_lo / 1023.0f;
        float a = 0.5f * (float)kmode * xs0;
        a = a - floorf(a);
        const float r = (float)kmode * (1.0f / 1023.0f);
        float a0 = 0.f, a1 = 0.f;
        if (j < 64) {  // wave-uniform: lanes of a wave share j-range
#pragma unroll 8
            for (int s = s_lo; s < s_lo + 512; ++s) {
                float bas = __builtin_amdgcn_cosf(a);
                a += r; a = a - floorf(a);
                a0 += bas * u0s[0][s];
                a1 += bas * u0s[1][s];
            }
        } else {
#pragma unroll 8
            for (int s = s_lo; s < s_lo + 512; ++s) {
                float bas = __builtin_amdgcn_sinf(a);
                a += r; a = a - floorf(a);
                a0 += bas * u0s[0][s];
                a1 += bas * u0s[1][s];
            }
        }
        part[half][0][j] = a0;
        part[half][1][j] = a1;
    }
    __syncthreads();
    if (t < 128) {
        const float sc = 1.0f / (float)SDIM;
        fr[0][j] = (part[0][0][j] + part[1][0][j]) * sc;
        fr[1][j] = (part[0][1][j] + part[1][1][j]) * sc;
    }
    __syncthreads();

    if (t < 128) {
        // layer 1
        {
            const float4* wp = (const float4*)(bw1 + (size_t)j * HDIM);
            float c0 = bb1[j], c1 = c0;
            for (int i4 = 0; i4 < 32; ++i4) {
                float4 wv = wp[i4];
                float4 x0 = *(const float4*)&fr[0][i4 * 4];
                float4 x1 = *(const float4*)&fr[1][i4 * 4];
                c0 += wv.x * x0.x + wv.y * x0.y + wv.z * x0.z + wv.w * x0.w;
                c1 += wv.x * x1.x + wv.y * x1.y + wv.z * x1.z + wv.w * x1.w;
            }
            hh[0][j] = fmaxf(c0, 0.f); hh[1][j] = fmaxf(c1, 0.f);
        }
        __syncthreads();
        // layer 2
        {
            const float4* wp = (const float4*)(bw2 + (size_t)j * HDIM);
            float c0 = bb2[j], c1 = c0;
            for (int i4 = 0; i4 < 32; ++i4) {
                float4 wv = wp[i4];
                float4 x0 = *(const float4*)&hh[0][i4 * 4];
                float4 x1 = *(const float4*)&hh[1][i4 * 4];
                c0 += wv.x * x0.x + wv.y * x0.y + wv.z * x0.z + wv.w * x0.w;
                c1 += wv.x * x1.x + wv.y * x1.y + wv.z * x1.z + wv.w * x1.w;
            }
            fr[0][j] = fmaxf(c0, 0.f); fr[1][j] = fmaxf(c1, 0.f);
        }
        __syncthreads();
        // layer 3 -> f16 branch
        {
            const float4* wp = (const float4*)(bw3 + (size_t)j * HDIM);
            float c0 = bb3[j], c1 = c0;
            for (int i4 = 0; i4 < 32; ++i4) {
                float4 wv = wp[i4];
                float4 x0 = *(const float4*)&fr[0][i4 * 4];
                float4 x1 = *(const float4*)&fr[1][i4 * 4];
                c0 += wv.x * x0.x + wv.y * x0.y + wv.z * x0.z + wv.w * x0.w;
                c1 += wv.x * x1.x + wv.y * x1.y + wv.z * x1.z + wv.w * x1.w;
            }
            branch_out[(size_t)(bb + 0) * HDIM + j] = __float2half(c0);
            branch_out[(size_t)(bb + 1) * HDIM + j] = __float2half(c1);
        }
    } else {
        __syncthreads();
        __syncthreads();
    }
}

// ---------------------------------------------------------------------------
// K2: final einsum via fp16 MFMA. out(256x4096) = br(256x128) @ t3^T * causal.
// 256 blocks (4 batch-tiles x 64 point-tiles of 64x64).
// ---------------------------------------------------------------------------
#define LDH 144
__global__ __launch_bounds__(256) void k_final(
    const __half* __restrict__ br_g, const __half* __restrict__ t3g,
    const float* __restrict__ xv, const float* __restrict__ tv,
    float* __restrict__ out) {
    __shared__ _Float16 brL[64 * LDH];
    __shared__ _Float16 ttL[64 * LDH];
    __shared__ float causL[64];

    const int t = threadIdx.x;
    const int rb = blockIdx.x >> 6;   // batch tile 0..3
    const int cb = blockIdx.x & 63;   // point tile 0..63

    if (t < 64) {
        int p = cb * 64 + t;
        float x = xv[p], tt = tv[p];
        causL[t] = (fabsf(x) <= tt) ? 1.f : 0.f;
    }

#pragma unroll
    for (int it = 0; it < 4; ++it) {
        int flat = t + 256 * it;
        int row = flat >> 4, c = flat & 15;
        *(float4*)&brL[row * LDH + c * 8] =
            *(const float4*)&br_g[(size_t)(rb * 64 + row) * HDIM + c * 8];
        *(float4*)&ttL[row * LDH + c * 8] =
            *(const float4*)&t3g[(size_t)(cb * 64 + row) * HDIM + c * 8];
    }
    __syncthreads();

    const int lane = t & 63;
    const int w = t >> 6;
    const int lm = lane & 15;
    const int q = lane >> 4;

    f32x4 acc[4] = {f32x4{0,0,0,0}, f32x4{0,0,0,0}, f32x4{0,0,0,0}, f32x4{0,0,0,0}};

    const _Float16* aBase = &brL[(16 * w + lm) * LDH + q * 8];
#pragma unroll
    for (int ks = 0; ks < 4; ++ks) {
        half8 af = *(const half8*)(aBase + ks * 32);
#pragma unroll
        for (int jt = 0; jt < 4; ++jt) {
            half8 bf = *(const half8*)&ttL[(16 * jt + lm) * LDH + q * 8 + ks * 32];
            acc[jt] = __builtin_amdgcn_mfma_f32_16x16x32_f16(af, bf, acc[jt], 0, 0, 0);
        }
    }

    // C/D layout: col=lane&15, row=(lane>>4)*4+reg (m89-verified)
#pragma unroll
    for (int jt = 0; jt < 4; ++jt) {
        int col = cb * 64 + 16 * jt + lm;
        float cz = causL[16 * jt + lm];
#pragma unroll
        for (int e = 0; e < 4; ++e) {
            int row = rb * 64 + 16 * w + q * 4 + e;
            out[(size_t)row * PDIM + col] = acc[jt][e] * cz;
        }
    }
}

// ---------------------------------------------------------------------------
extern "C" void kernel_launch(void* const* d_in, const int* in_sizes, int n_in,
                              void* d_out, int out_size, void* d_ws, size_t ws_size,
                              hipStream_t stream) {
    const float* u0  = (const float*)d_in[0];
    const float* xv  = (const float*)d_in[1];
    const float* tv  = (const float*)d_in[2];
    const float* bw1 = (const float*)d_in[3];
    const float* bb1 = (const float*)d_in[4];
    const float* bw2 = (const float*)d_in[5];
    const float* bb2 = (const float*)d_in[6];
    const float* bw3 = (const float*)d_in[7];
    const float* bb3 = (const float*)d_in[8];
    const float* tw1 = (const float*)d_in[9];
    const float* tb1 = (const float*)d_in[10];
    const float* tw2 = (const float*)d_in[11];
    const float* tb2 = (const float*)d_in[12];
    const float* tw3 = (const float*)d_in[13];
    const float* tb3 = (const float*)d_in[14];

    char* wsb = (char*)d_ws;
    __half* branch_out = (__half*)(wsb + WSB_BRANCH);
    __half* t3g        = (__half*)(wsb + WSB_T3);
    float* out = (float*)d_out;

    hipLaunchKernelGGL(k_fused, dim3(384), dim3(256), 0, stream,
                       u0, xv, tv, bw1, bb1, bw2, bb2, bw3, bb3,
                       tw1, tb1, tw2, tb2, tw3, tb3, branch_out, t3g);
    hipLaunchKernelGGL(k_final, dim3(256), dim3(256), 0, stream,
                       branch_out, t3g, xv, tv, out);
}